// Round 10
// baseline (30.086 us; speedup 1.0000x reference)
//
#include <hip/hip_runtime.h>
#include <hip/hip_bf16.h>

// Radon transform: x (4,1,384,384) f32 -> out (4,460,64) f32
// pad = 38, Hp = Wp = 460, N_ANGLES = 64.
//
// R10: R9 structure (batch-interleaved bf16 texels, one uint4 per stencil
// row -> 2 loads/iter; normal+transposed layouts L2-resident; wave = 4y x
// 16xx x 4 batches; 128-thread blocks; 1D pad kernel) with the inner loop
// unrolled x4 for 4x memory-level parallelism (8 independent dwordx4 loads
// in flight per thread). Discriminates latency-bound vs pipe-bound.

constexpr int IMG = 384;
constexpr int PAD = 38;
constexpr int P   = 460;   // Hp = Wp
constexpr int NA  = 64;
constexpr int NB  = 4;
constexpr int B_  = 6;               // zero border
constexpr int O_  = PAD - B_;        // 32
constexpr int E_  = IMG + 2 * B_;    // 396

__device__ __forceinline__ unsigned int f2bfu(float f) {
    __hip_bfloat16 h = __float2bfloat16(f);   // RNE
    return (unsigned int)__builtin_bit_cast(unsigned short, h);
}
__device__ __forceinline__ float bf_lo(unsigned int w) { return __uint_as_float(w << 16); }
__device__ __forceinline__ float bf_hi(unsigned int w) { return __uint_as_float(w & 0xffff0000u); }

// 1D pad + batch-interleave + both layouts. One thread per texel position.
__global__ __launch_bounds__(256) void pad4_kernel(const float* __restrict__ x,
                                                   uint2* __restrict__ pb,
                                                   uint2* __restrict__ pbT) {
    const int idx = blockIdx.x * 256 + threadIdx.x;
    if (idx >= E_ * E_) return;
    const int iy = idx / E_;
    const int ix = idx - iy * E_;
    const int py = iy - B_, px = ix - B_;       // core coords
    uint2 t = make_uint2(0u, 0u);
    if ((unsigned)py < (unsigned)IMG && (unsigned)px < (unsigned)IMG) {
        const int o = py * IMG + px;
        t.x = f2bfu(x[o])                 | (f2bfu(x[IMG * IMG + o])     << 16);
        t.y = f2bfu(x[2 * IMG * IMG + o]) | (f2bfu(x[3 * IMG * IMG + o]) << 16);
    }
    pb[iy * E_ + ix]  = t;      // coalesced
    pbT[ix * E_ + iy] = t;      // scattered 8B; L2 absorbs (1.25 MB total)
}

__global__ __launch_bounds__(128) void radon_kernel(const uint2* __restrict__ pb,
                                                    const uint2* __restrict__ pbT,
                                                    float* __restrict__ out) {
    const int lane = threadIdx.x & 63;
    const int wv   = threadIdx.x >> 6;       // 0..1
    const int l    = lane & 15;              // lane in group
    const int g    = lane >> 4;              // y-group in wave
    const int a    = blockIdx.y;
    const int y    = blockIdx.x * 8 + wv * 4 + g;

    const float th = (2.8125f * (float)a) * 0.017453292519943295f;
    float s, c;
    __sincosf(th, &s, &c);

    const float yf = (float)(y < P ? y : P - 1);
    const float ys = (2.0f * yf + 1.0f) / 460.0f - 1.0f;
    // fix = c*xx + A ; fiy = s*xx + By (padded-image pixel coords)
    const float A  = fmaf(-s, ys, 1.0f) * 230.0f - 0.5f - 229.5f * c;
    const float By = fmaf( c, ys, 1.0f) * 230.0f - 0.5f - 229.5f * s;

    // xx-interval where the stencil can touch the core ([36,424] conservative;
    // rcp error + floor slack covered by +/-2 and the 6px border).
    const float rc = __builtin_amdgcn_rcpf(c);
    const float rs = __builtin_amdgcn_rcpf(s);
    float t0 = (36.0f - A) * rc, t1 = (424.0f - A) * rc;
    float lo = fmaxf(0.0f,   fminf(t0, t1));
    float hi = fminf(459.0f, fmaxf(t0, t1));
    t0 = (36.0f - By) * rs; t1 = (424.0f - By) * rs;
    lo = fmaxf(lo, fminf(t0, t1));
    hi = fminf(hi, fmaxf(t0, t1));

    int glo = max(0, (int)floorf(lo) - 2);
    glo = min(glo, P);                       // saturate +inf case, avoid wrap
    int ghi = min(P - 1, (int)ceilf(hi) + 2);
    if (y >= P) { glo = 1; ghi = 0; }

    // Layout: row coord v should step slowly with xx -> |cv| = min(|c|,|s|).
    const bool  useT = fabsf(s) > fabsf(c);
    const float cu = useT ? s  : c;
    const float Au = useT ? By : A;
    const float cv = useT ? c  : s;
    const float Av = useT ? A  : By;
    const uint2* __restrict__ base = useT ? pbT : pb;

    float acc0 = 0.0f, acc1 = 0.0f, acc2 = 0.0f, acc3 = 0.0f;
    float xxf = (float)(glo + l);
    #pragma unroll 4
    for (int xx = glo + l; xx <= ghi; xx += 16, xxf += 16.0f) {
        const float u   = fmaf(cu, xxf, Au);
        const float v   = fmaf(cv, xxf, Av);
        const float u0f = floorf(u);
        const float v0f = floorf(v);
        const float wu  = u - u0f;
        const float wvv = v - v0f;
        const int idx = (int)fmaf(v0f, (float)E_, u0f) - (O_ * E_ + O_);

        // One 16B load per stencil row: texels (u0,v) and (u0+1,v).
        const uint4 R0 = *reinterpret_cast<const uint4*>(base + idx);
        const uint4 R1 = *reinterpret_cast<const uint4*>(base + idx + E_);

        {   // batch 0: lo halves of words 0 (u0) and 2 (u0+1)
            const float top = fmaf(wu, bf_lo(R0.z) - bf_lo(R0.x), bf_lo(R0.x));
            const float bot = fmaf(wu, bf_lo(R1.z) - bf_lo(R1.x), bf_lo(R1.x));
            acc0 += fmaf(wvv, bot - top, top);
        }
        {   // batch 1: hi halves of words 0/2
            const float top = fmaf(wu, bf_hi(R0.z) - bf_hi(R0.x), bf_hi(R0.x));
            const float bot = fmaf(wu, bf_hi(R1.z) - bf_hi(R1.x), bf_hi(R1.x));
            acc1 += fmaf(wvv, bot - top, top);
        }
        {   // batch 2: lo halves of words 1/3
            const float top = fmaf(wu, bf_lo(R0.w) - bf_lo(R0.y), bf_lo(R0.y));
            const float bot = fmaf(wu, bf_lo(R1.w) - bf_lo(R1.y), bf_lo(R1.y));
            acc2 += fmaf(wvv, bot - top, top);
        }
        {   // batch 3: hi halves of words 1/3
            const float top = fmaf(wu, bf_hi(R0.w) - bf_hi(R0.y), bf_hi(R0.y));
            const float bot = fmaf(wu, bf_hi(R1.w) - bf_hi(R1.y), bf_hi(R1.y));
            acc3 += fmaf(wvv, bot - top, top);
        }
    }

    // 4-step butterfly within each 16-lane group; 4 independent chains (ILP)
    #pragma unroll
    for (int m = 1; m <= 8; m <<= 1) {
        acc0 += __shfl_xor(acc0, m);
        acc1 += __shfl_xor(acc1, m);
        acc2 += __shfl_xor(acc2, m);
        acc3 += __shfl_xor(acc3, m);
    }

    if (l == 0 && y < P) {
        out[(0 * P + y) * NA + a] = acc0 / 460.0f;
        out[(1 * P + y) * NA + a] = acc1 / 460.0f;
        out[(2 * P + y) * NA + a] = acc2 / 460.0f;
        out[(3 * P + y) * NA + a] = acc3 / 460.0f;
    }
}

// ---- Fallback (no/undersized workspace): bounds-checked direct sampling ----
__device__ __forceinline__ float samp(const float* __restrict__ img, int iy, int ix) {
    unsigned uy = (unsigned)(iy - PAD);
    unsigned ux = (unsigned)(ix - PAD);
    return (uy < (unsigned)IMG && ux < (unsigned)IMG) ? img[uy * IMG + ux] : 0.0f;
}

__global__ __launch_bounds__(256) void radon_fallback(const float* __restrict__ x,
                                                      float* __restrict__ out) {
    const int wid  = blockIdx.x * 4 + (threadIdx.x >> 6);
    const int lane = threadIdx.x & 63;
    if (wid >= NB * NA * P) return;
    const int y  = wid % P;
    const int ba = wid / P;
    const int a  = ba % NA;
    const int b  = ba / NA;
    const float th = (2.8125f * (float)a) * 0.017453292519943295f;
    float s, c;
    __sincosf(th, &s, &c);
    const float ysy = (2.0f * (float)y + 1.0f) / 460.0f - 1.0f;
    const float* img = x + b * IMG * IMG;
    float acc = 0.0f;
    for (int xx = lane; xx < P; xx += 64) {
        const float xsx = (2.0f * (float)xx + 1.0f) / 460.0f - 1.0f;
        const float gx = c * xsx - s * ysy;
        const float gy = s * xsx + c * ysy;
        const float fix = ((gx + 1.0f) * 460.0f - 1.0f) * 0.5f;
        const float fiy = ((gy + 1.0f) * 460.0f - 1.0f) * 0.5f;
        const float ix0f = floorf(fix);
        const float iy0f = floorf(fiy);
        const float wx = fix - ix0f;
        const float wy = fiy - iy0f;
        const int ix0 = (int)ix0f;
        const int iy0 = (int)iy0f;
        const float v00 = samp(img, iy0,     ix0);
        const float v01 = samp(img, iy0,     ix0 + 1);
        const float v10 = samp(img, iy0 + 1, ix0);
        const float v11 = samp(img, iy0 + 1, ix0 + 1);
        acc += v00 * ((1.0f - wy) * (1.0f - wx))
             + v01 * ((1.0f - wy) * wx)
             + v10 * (wy * (1.0f - wx))
             + v11 * (wy * wx);
    }
    #pragma unroll
    for (int off = 32; off; off >>= 1) acc += __shfl_xor(acc, off);
    if (lane == 0) out[(b * P + y) * NA + a] = acc / 460.0f;
}

extern "C" void kernel_launch(void* const* d_in, const int* in_sizes, int n_in,
                              void* d_out, int out_size, void* d_ws, size_t ws_size,
                              hipStream_t stream) {
    const float* x = (const float*)d_in[0];
    float* out = (float*)d_out;

    const size_t layer = (size_t)E_ * E_;            // texels per layout
    const size_t need  = 2 * layer * sizeof(uint2);  // ~2.5 MB

    if (ws_size >= need) {
        uint2* pb  = (uint2*)d_ws;
        uint2* pbT = pb + layer;
        const int pad_blocks = (E_ * E_ + 255) / 256;    // 613
        pad4_kernel<<<pad_blocks, 256, 0, stream>>>(x, pb, pbT);
        dim3 grid((P + 7) / 8, NA);                      // (58, 64) x 2-wave blocks
        radon_kernel<<<grid, 128, 0, stream>>>(pb, pbT, out);
    } else {
        const int total_waves = NB * NA * P;
        const int blocks = (total_waves + 3) / 4;
        radon_fallback<<<blocks, 256, 0, stream>>>(x, out);
    }
}

// Round 11
// 28.605 us; speedup vs baseline: 1.0518x; 1.0518x over previous
//
#include <hip/hip_runtime.h>
#include <hip/hip_bf16.h>

// Radon transform: x (4,1,384,384) f32 -> out (4,460,64) f32
// pad = 38, Hp = Wp = 460, N_ANGLES = 64.
//
// R11 = R9 (best: 28.94 us). Batch-interleaved bf16 texels, one uint4 per
// stencil row -> 2 load instructions/iter; normal+transposed layouts
// L2-resident (2.5 MB); wave = 4y x 16xx x 4 batches; 128-thread blocks;
// 1D pad kernel. R8 (2x occupancy) and R10 (4x MLP unroll) were both
// neutral -> kernel saturates the L1 line-transaction pipe; this is the
// structural optimum of this formulation.

constexpr int IMG = 384;
constexpr int PAD = 38;
constexpr int P   = 460;   // Hp = Wp
constexpr int NA  = 64;
constexpr int NB  = 4;
constexpr int B_  = 6;               // zero border
constexpr int O_  = PAD - B_;        // 32
constexpr int E_  = IMG + 2 * B_;    // 396

__device__ __forceinline__ unsigned int f2bfu(float f) {
    __hip_bfloat16 h = __float2bfloat16(f);   // RNE
    return (unsigned int)__builtin_bit_cast(unsigned short, h);
}
__device__ __forceinline__ float bf_lo(unsigned int w) { return __uint_as_float(w << 16); }
__device__ __forceinline__ float bf_hi(unsigned int w) { return __uint_as_float(w & 0xffff0000u); }

// 1D pad + batch-interleave + both layouts. One thread per texel position.
__global__ __launch_bounds__(256) void pad4_kernel(const float* __restrict__ x,
                                                   uint2* __restrict__ pb,
                                                   uint2* __restrict__ pbT) {
    const int idx = blockIdx.x * 256 + threadIdx.x;
    if (idx >= E_ * E_) return;
    const int iy = idx / E_;
    const int ix = idx - iy * E_;
    const int py = iy - B_, px = ix - B_;       // core coords
    uint2 t = make_uint2(0u, 0u);
    if ((unsigned)py < (unsigned)IMG && (unsigned)px < (unsigned)IMG) {
        const int o = py * IMG + px;
        t.x = f2bfu(x[o])                 | (f2bfu(x[IMG * IMG + o])     << 16);
        t.y = f2bfu(x[2 * IMG * IMG + o]) | (f2bfu(x[3 * IMG * IMG + o]) << 16);
    }
    pb[iy * E_ + ix]  = t;      // coalesced
    pbT[ix * E_ + iy] = t;      // scattered 8B; L2 absorbs (1.25 MB total)
}

__global__ __launch_bounds__(128) void radon_kernel(const uint2* __restrict__ pb,
                                                    const uint2* __restrict__ pbT,
                                                    float* __restrict__ out) {
    const int lane = threadIdx.x & 63;
    const int wv   = threadIdx.x >> 6;       // 0..1
    const int l    = lane & 15;              // lane in group
    const int g    = lane >> 4;              // y-group in wave
    const int a    = blockIdx.y;
    const int y    = blockIdx.x * 8 + wv * 4 + g;

    const float th = (2.8125f * (float)a) * 0.017453292519943295f;
    float s, c;
    __sincosf(th, &s, &c);

    const float yf = (float)(y < P ? y : P - 1);
    const float ys = (2.0f * yf + 1.0f) / 460.0f - 1.0f;
    // fix = c*xx + A ; fiy = s*xx + By (padded-image pixel coords)
    const float A  = fmaf(-s, ys, 1.0f) * 230.0f - 0.5f - 229.5f * c;
    const float By = fmaf( c, ys, 1.0f) * 230.0f - 0.5f - 229.5f * s;

    // xx-interval where the stencil can touch the core ([36,424] conservative;
    // rcp error + floor slack covered by +/-2 and the 6px border).
    const float rc = __builtin_amdgcn_rcpf(c);
    const float rs = __builtin_amdgcn_rcpf(s);
    float t0 = (36.0f - A) * rc, t1 = (424.0f - A) * rc;
    float lo = fmaxf(0.0f,   fminf(t0, t1));
    float hi = fminf(459.0f, fmaxf(t0, t1));
    t0 = (36.0f - By) * rs; t1 = (424.0f - By) * rs;
    lo = fmaxf(lo, fminf(t0, t1));
    hi = fminf(hi, fmaxf(t0, t1));

    int glo = max(0, (int)floorf(lo) - 2);
    glo = min(glo, P);                       // saturate +inf case, avoid wrap
    int ghi = min(P - 1, (int)ceilf(hi) + 2);
    if (y >= P) { glo = 1; ghi = 0; }

    // Layout: row coord v should step slowly with xx -> |cv| = min(|c|,|s|).
    const bool  useT = fabsf(s) > fabsf(c);
    const float cu = useT ? s  : c;
    const float Au = useT ? By : A;
    const float cv = useT ? c  : s;
    const float Av = useT ? A  : By;
    const uint2* __restrict__ base = useT ? pbT : pb;

    float acc0 = 0.0f, acc1 = 0.0f, acc2 = 0.0f, acc3 = 0.0f;
    float xxf = (float)(glo + l);
    #pragma unroll 2
    for (int xx = glo + l; xx <= ghi; xx += 16, xxf += 16.0f) {
        const float u   = fmaf(cu, xxf, Au);
        const float v   = fmaf(cv, xxf, Av);
        const float u0f = floorf(u);
        const float v0f = floorf(v);
        const float wu  = u - u0f;
        const float wvv = v - v0f;
        const int idx = (int)fmaf(v0f, (float)E_, u0f) - (O_ * E_ + O_);

        // One 16B load per stencil row: texels (u0,v) and (u0+1,v).
        const uint4 R0 = *reinterpret_cast<const uint4*>(base + idx);
        const uint4 R1 = *reinterpret_cast<const uint4*>(base + idx + E_);

        {   // batch 0: lo halves of words 0 (u0) and 2 (u0+1)
            const float top = fmaf(wu, bf_lo(R0.z) - bf_lo(R0.x), bf_lo(R0.x));
            const float bot = fmaf(wu, bf_lo(R1.z) - bf_lo(R1.x), bf_lo(R1.x));
            acc0 += fmaf(wvv, bot - top, top);
        }
        {   // batch 1: hi halves of words 0/2
            const float top = fmaf(wu, bf_hi(R0.z) - bf_hi(R0.x), bf_hi(R0.x));
            const float bot = fmaf(wu, bf_hi(R1.z) - bf_hi(R1.x), bf_hi(R1.x));
            acc1 += fmaf(wvv, bot - top, top);
        }
        {   // batch 2: lo halves of words 1/3
            const float top = fmaf(wu, bf_lo(R0.w) - bf_lo(R0.y), bf_lo(R0.y));
            const float bot = fmaf(wu, bf_lo(R1.w) - bf_lo(R1.y), bf_lo(R1.y));
            acc2 += fmaf(wvv, bot - top, top);
        }
        {   // batch 3: hi halves of words 1/3
            const float top = fmaf(wu, bf_hi(R0.w) - bf_hi(R0.y), bf_hi(R0.y));
            const float bot = fmaf(wu, bf_hi(R1.w) - bf_hi(R1.y), bf_hi(R1.y));
            acc3 += fmaf(wvv, bot - top, top);
        }
    }

    // 4-step butterfly within each 16-lane group; 4 independent chains (ILP)
    #pragma unroll
    for (int m = 1; m <= 8; m <<= 1) {
        acc0 += __shfl_xor(acc0, m);
        acc1 += __shfl_xor(acc1, m);
        acc2 += __shfl_xor(acc2, m);
        acc3 += __shfl_xor(acc3, m);
    }

    if (l == 0 && y < P) {
        out[(0 * P + y) * NA + a] = acc0 / 460.0f;
        out[(1 * P + y) * NA + a] = acc1 / 460.0f;
        out[(2 * P + y) * NA + a] = acc2 / 460.0f;
        out[(3 * P + y) * NA + a] = acc3 / 460.0f;
    }
}

// ---- Fallback (no/undersized workspace): bounds-checked direct sampling ----
__device__ __forceinline__ float samp(const float* __restrict__ img, int iy, int ix) {
    unsigned uy = (unsigned)(iy - PAD);
    unsigned ux = (unsigned)(ix - PAD);
    return (uy < (unsigned)IMG && ux < (unsigned)IMG) ? img[uy * IMG + ux] : 0.0f;
}

__global__ __launch_bounds__(256) void radon_fallback(const float* __restrict__ x,
                                                      float* __restrict__ out) {
    const int wid  = blockIdx.x * 4 + (threadIdx.x >> 6);
    const int lane = threadIdx.x & 63;
    if (wid >= NB * NA * P) return;
    const int y  = wid % P;
    const int ba = wid / P;
    const int a  = ba % NA;
    const int b  = ba / NA;
    const float th = (2.8125f * (float)a) * 0.017453292519943295f;
    float s, c;
    __sincosf(th, &s, &c);
    const float ysy = (2.0f * (float)y + 1.0f) / 460.0f - 1.0f;
    const float* img = x + b * IMG * IMG;
    float acc = 0.0f;
    for (int xx = lane; xx < P; xx += 64) {
        const float xsx = (2.0f * (float)xx + 1.0f) / 460.0f - 1.0f;
        const float gx = c * xsx - s * ysy;
        const float gy = s * xsx + c * ysy;
        const float fix = ((gx + 1.0f) * 460.0f - 1.0f) * 0.5f;
        const float fiy = ((gy + 1.0f) * 460.0f - 1.0f) * 0.5f;
        const float ix0f = floorf(fix);
        const float iy0f = floorf(fiy);
        const float wx = fix - ix0f;
        const float wy = fiy - iy0f;
        const int ix0 = (int)ix0f;
        const int iy0 = (int)iy0f;
        const float v00 = samp(img, iy0,     ix0);
        const float v01 = samp(img, iy0,     ix0 + 1);
        const float v10 = samp(img, iy0 + 1, ix0);
        const float v11 = samp(img, iy0 + 1, ix0 + 1);
        acc += v00 * ((1.0f - wy) * (1.0f - wx))
             + v01 * ((1.0f - wy) * wx)
             + v10 * (wy * (1.0f - wx))
             + v11 * (wy * wx);
    }
    #pragma unroll
    for (int off = 32; off; off >>= 1) acc += __shfl_xor(acc, off);
    if (lane == 0) out[(b * P + y) * NA + a] = acc / 460.0f;
}

extern "C" void kernel_launch(void* const* d_in, const int* in_sizes, int n_in,
                              void* d_out, int out_size, void* d_ws, size_t ws_size,
                              hipStream_t stream) {
    const float* x = (const float*)d_in[0];
    float* out = (float*)d_out;

    const size_t layer = (size_t)E_ * E_;            // texels per layout
    const size_t need  = 2 * layer * sizeof(uint2);  // ~2.5 MB

    if (ws_size >= need) {
        uint2* pb  = (uint2*)d_ws;
        uint2* pbT = pb + layer;
        const int pad_blocks = (E_ * E_ + 255) / 256;    // 613
        pad4_kernel<<<pad_blocks, 256, 0, stream>>>(x, pb, pbT);
        dim3 grid((P + 7) / 8, NA);                      // (58, 64) x 2-wave blocks
        radon_kernel<<<grid, 128, 0, stream>>>(pb, pbT, out);
    } else {
        const int total_waves = NB * NA * P;
        const int blocks = (total_waves + 3) / 4;
        radon_fallback<<<blocks, 256, 0, stream>>>(x, out);
    }
}